// Round 22
// baseline (156.615 us; speedup 1.0000x reference)
//
#include <hip/hip_runtime.h>
#include <stdint.h>
#include <type_traits>

#define M_DIM 16384
#define N_DIM 2048
#define K_DIM 2048

typedef __bf16 bf16_t;
typedef __bf16 bf16x8 __attribute__((ext_vector_type(8)));
typedef __bf16 bf16x4 __attribute__((ext_vector_type(4)));
typedef float f32x4 __attribute__((ext_vector_type(4)));

template <int N> using ic = std::integral_constant<int, N>;

#define SB0() __builtin_amdgcn_sched_barrier(0)

__device__ __forceinline__ void gload_lds16(const void* g, void* l) {
  __builtin_amdgcn_global_load_lds(
      (const __attribute__((address_space(1))) void*)g,
      (__attribute__((address_space(3))) void*)l, 16, 0, 0);
}

// Fused converter (r12/r15-verified best): blocks [0,NXB) cvt x (bf16 RNE);
// blocks [NXB,NXB+NWB) cvt w with sign() (exact in bf16).
#define NXB (M_DIM * K_DIM / 2048)
#define NWB (N_DIM * K_DIM / 2048)
__global__ void cvt_fused(const float* __restrict__ x, const float* __restrict__ w,
                          bf16_t* __restrict__ xb, bf16_t* __restrict__ wb) {
  int b = blockIdx.x;
  const float* in = (b < NXB) ? x : w;
  bf16_t* out = (b < NXB) ? xb : wb;
  bool sign = (b >= NXB);
  if (b >= NXB) b -= NXB;
  long long i = ((long long)b * 256 + threadIdx.x) * 8;
  const float4* p = (const float4*)(in + i);
  float4 v0 = p[0];
  float4 v1 = p[1];
  float f[8] = {v0.x, v0.y, v0.z, v0.w, v1.x, v1.y, v1.z, v1.w};
  bf16x8 r;
#pragma unroll
  for (int j = 0; j < 8; ++j) {
    float v = f[j];
    if (sign) v = (v > 0.f) ? 1.f : ((v < 0.f) ? -1.f : 0.f);
    r[j] = (bf16_t)v;
  }
  *(bf16x8*)(out + i) = r;
}

// ============================================================================
// Round-22: r19 schedule (verified 118.5us GEMM, 4 barriers/tile, each
// gating a proven hazard) + INTRA-PHASE counted-lgkm streaming.
// Change vs r19 (intra-phase only; barriers/staging/vmcnt untouched):
// each phase's reads are issued in pinned groups ordered so consumers
// become available incrementally, and the single lgkmcnt(0) drain is
// replaced by counted waits interleaved with MFMA sub-clusters:
//   P1: issue [bL(4)+a0(2)]|[a1]|[a2]|[a3]; lgkm(6)->MFMA(a0,4);
//       lgkm(4)->a1; lgkm(2)->a2; lgkm(0)->a3.   (12 reads stream under Q1)
//   P2: issue [bH0(2)]|[bH1(2)]; stage aLo+bLo(t+2); lgkm(2)->MFMA(nt0,8);
//       lgkm(0)->MFMA(nt1,8).
//   P3: issue [a4,a5]|[a6,a7]; stage bHi(t+2); lgkm(4)->MFMA(mt45,8);
//       lgkm(0)->MFMA(mt67,8).
//   P4: unchanged (stage aHi; vmcnt(8); BAR; Q4 reg-only; no end-BAR).
// Rationale: with the pre-MFMA barriers removed (r19), the per-phase
// lgkm(0) drain exposes the full ds_read burst latency per wave; barriers
// keep the 2 waves/SIMD in-phase so both read together -> ~50% MfmaUtil.
// Counted waits stream reads under the wave's OWN MFMA. (r6's version of
// this was neutral because its pre-MFMA barrier already absorbed latency.)
// DS ops complete in-order per wave; SB0 pins issue order (rule 18: SB0
// after every inline-asm wait).
// ============================================================================
__global__ __launch_bounds__(512, 2) void gemm12(const bf16_t* __restrict__ A,
                                                 const bf16_t* __restrict__ B,
                                                 const float* __restrict__ alpha_p,
                                                 float* __restrict__ C) {
  extern __shared__ char smem[];  // buf(t&1): A @ tb+0 (32KB), B @ tb+32768

  const int tid = threadIdx.x;
  const int lane = tid & 63;
  const int wid = tid >> 6;
  const int wm = wid >> 2;   // 0..1 -> rows wm*128..+127
  const int wn = wid & 3;    // 0..3 -> cols wn*64..+63

  // XCD-aware bijective swizzle (512 blocks, 512 % 8 == 0)
  const int bid = blockIdx.x;
  const int swz = (bid & 7) * 64 + (bid >> 3);
  const int bm = swz >> 3;   // 0..63
  const int bn = swz & 7;    // 0..7

  const int q = lane >> 4;   // 16B col-slot within K
  const int r15 = lane & 15; // frag row

  // ---- Fragment LDS byte bases ----
  const int swc = (r15 & 7) << 4;
  int aoff[2], boffL[2], boffH[2];
#pragma unroll
  for (int k = 0; k < 2; ++k) {
    int ck = (k * 64 + q * 16) ^ swc;
    aoff[k] = (wm * 128 + r15) * 128 + ck;                 // + mt*2048
    boffL[k] = 32768 + (wn * 32 + r15) * 128 + ck;         // + nt*2048 (nt 0,1)
    boffH[k] = 32768 + 16384 + (wn * 32 + r15) * 128 + ck; // + (nt-2)*2048
  }

  // ---- Stage sources: inverse-swizzled global, linear LDS dest ----
  const char* asrc0;
  {
    int P = tid * 16;
    int row = P >> 7;
    int lcol = (P & 127) ^ ((row & 7) << 4);
    asrc0 = (const char*)A + (size_t)(bm * 256 + row) * (K_DIM * 2) + lcol;
  }
  const char* bsrc[4];
#pragma unroll
  for (int c = 0; c < 4; ++c) {
    int P = c * 8192 + tid * 16;
    int lr = P >> 7;                       // LDS row 0..255
    int grow;
    if (lr < 128) grow = (lr >> 5) * 64 + (lr & 31);          // bLo
    else { int l2 = lr - 128; grow = (l2 >> 5) * 64 + 32 + (l2 & 31); }  // bHi
    int lcol = (P & 127) ^ ((lr & 7) << 4);
    bsrc[c] = (const char*)B + (size_t)(bn * 256 + grow) * (K_DIM * 2) + lcol;
  }
  const int dsto = wid * 1024;

  f32x4 acc[8][4];
#pragma unroll
  for (int mt = 0; mt < 8; ++mt)
#pragma unroll
    for (int nt = 0; nt < 4; ++nt) acc[mt][nt] = (f32x4){0.f, 0.f, 0.f, 0.f};

  // ---- Prologue: stage tiles 0,1 (16 loads); wait tile 0 (8 younger) ----
#pragma unroll
  for (int t = 0; t < 2; ++t) {
#pragma unroll
    for (int j = 0; j < 4; ++j)
      gload_lds16(asrc0 + (size_t)j * 262144 + t * 128,
                  smem + t * 65536 + j * 8192 + dsto);
#pragma unroll
    for (int c = 0; c < 4; ++c)
      gload_lds16(bsrc[c] + t * 128, smem + t * 65536 + 32768 + c * 8192 + dsto);
  }
  asm volatile("s_waitcnt vmcnt(8)" ::: "memory");
  SB0();
  __builtin_amdgcn_s_barrier();
  SB0();

  // One K-tile (BK=64, 4 phases, 4 barriers). U = t&1. MODE: 0 steady
  // (stage t+2, vmcnt(8)); 1 = t=30 (no stage, vmcnt(0)); 2 = t=31 (none).
  auto kstep = [&](auto UC, auto MC) {
    constexpr int U = UC.value;
    constexpr int MODE = MC.value;
    constexpr int TB = U * 65536;
    constexpr int GOFF = (U + 2) * 128;

    bf16x8 a[4][2], bL[2][2], bH[2][2];

    // ---- P1: [bL+a0]|a1|a2|a3; counted-lgkm streamed Q1; BAR ----
#pragma unroll
    for (int nt = 0; nt < 2; ++nt)
#pragma unroll
      for (int k = 0; k < 2; ++k)
        bL[nt][k] = *(const bf16x8*)(smem + TB + boffL[k] + nt * 2048);
#pragma unroll
    for (int k = 0; k < 2; ++k)
      a[0][k] = *(const bf16x8*)(smem + TB + aoff[k] + 0 * 2048);
    SB0();
#pragma unroll
    for (int k = 0; k < 2; ++k)
      a[1][k] = *(const bf16x8*)(smem + TB + aoff[k] + 1 * 2048);
    SB0();
#pragma unroll
    for (int k = 0; k < 2; ++k)
      a[2][k] = *(const bf16x8*)(smem + TB + aoff[k] + 2 * 2048);
    SB0();
#pragma unroll
    for (int k = 0; k < 2; ++k)
      a[3][k] = *(const bf16x8*)(smem + TB + aoff[k] + 3 * 2048);
    SB0();
    __builtin_amdgcn_s_setprio(1);
    asm volatile("s_waitcnt lgkmcnt(6)" ::: "memory");  // bL+a0 done
    SB0();
#pragma unroll
    for (int k = 0; k < 2; ++k)
#pragma unroll
      for (int nt = 0; nt < 2; ++nt)
        acc[0][nt] = __builtin_amdgcn_mfma_f32_16x16x32_bf16(
            a[0][k], bL[nt][k], acc[0][nt], 0, 0, 0);
    asm volatile("s_waitcnt lgkmcnt(4)" ::: "memory");  // a1 done
    SB0();
#pragma unroll
    for (int k = 0; k < 2; ++k)
#pragma unroll
      for (int nt = 0; nt < 2; ++nt)
        acc[1][nt] = __builtin_amdgcn_mfma_f32_16x16x32_bf16(
            a[1][k], bL[nt][k], acc[1][nt], 0, 0, 0);
    asm volatile("s_waitcnt lgkmcnt(2)" ::: "memory");  // a2 done
    SB0();
#pragma unroll
    for (int k = 0; k < 2; ++k)
#pragma unroll
      for (int nt = 0; nt < 2; ++nt)
        acc[2][nt] = __builtin_amdgcn_mfma_f32_16x16x32_bf16(
            a[2][k], bL[nt][k], acc[2][nt], 0, 0, 0);
    asm volatile("s_waitcnt lgkmcnt(0)" ::: "memory");  // a3 done
    SB0();
#pragma unroll
    for (int k = 0; k < 2; ++k)
#pragma unroll
      for (int nt = 0; nt < 2; ++nt)
        acc[3][nt] = __builtin_amdgcn_mfma_f32_16x16x32_bf16(
            a[3][k], bL[nt][k], acc[3][nt], 0, 0, 0);
    __builtin_amdgcn_s_setprio(0);
    SB0();
    __builtin_amdgcn_s_barrier();   // aLo/bLo regions dead block-wide

    // ---- P2: [bH0]|[bH1]; stage aLo+bLo(t+2); streamed Q2; BAR ----
#pragma unroll
    for (int k = 0; k < 2; ++k)
      bH[0][k] = *(const bf16x8*)(smem + TB + boffH[k] + 0 * 2048);
    SB0();
#pragma unroll
    for (int k = 0; k < 2; ++k)
      bH[1][k] = *(const bf16x8*)(smem + TB + boffH[k] + 1 * 2048);
    if constexpr (MODE == 0) {
      gload_lds16(asrc0 + 0 * 262144 + GOFF, smem + TB + 0 * 8192 + dsto);
      gload_lds16(asrc0 + 2 * 262144 + GOFF, smem + TB + 2 * 8192 + dsto);
      gload_lds16(bsrc[0] + GOFF, smem + TB + 32768 + 0 * 8192 + dsto);
      gload_lds16(bsrc[1] + GOFF, smem + TB + 32768 + 1 * 8192 + dsto);
    }
    SB0();
    __builtin_amdgcn_s_setprio(1);
    asm volatile("s_waitcnt lgkmcnt(2)" ::: "memory");  // bH0 done
    SB0();
#pragma unroll
    for (int k = 0; k < 2; ++k)
#pragma unroll
      for (int mt = 0; mt < 4; ++mt)
        acc[mt][2] = __builtin_amdgcn_mfma_f32_16x16x32_bf16(
            a[mt][k], bH[0][k], acc[mt][2], 0, 0, 0);
    asm volatile("s_waitcnt lgkmcnt(0)" ::: "memory");  // bH1 done
    SB0();
#pragma unroll
    for (int k = 0; k < 2; ++k)
#pragma unroll
      for (int mt = 0; mt < 4; ++mt)
        acc[mt][3] = __builtin_amdgcn_mfma_f32_16x16x32_bf16(
            a[mt][k], bH[1][k], acc[mt][3], 0, 0, 0);
    __builtin_amdgcn_s_setprio(0);
    SB0();
    __builtin_amdgcn_s_barrier();   // bHi region dead block-wide

    // ---- P3: [a4,a5]|[a6,a7]; stage bHi(t+2); streamed Q3; BAR ----
#pragma unroll
    for (int mt = 0; mt < 2; ++mt)
#pragma unroll
      for (int k = 0; k < 2; ++k)
        a[mt][k] = *(const bf16x8*)(smem + TB + aoff[k] + (4 + mt) * 2048);
    SB0();
#pragma unroll
    for (int mt = 2; mt < 4; ++mt)
#pragma unroll
      for (int k = 0; k < 2; ++k)
        a[mt][k] = *(const bf16x8*)(smem + TB + aoff[k] + (4 + mt) * 2048);
    if constexpr (MODE == 0) {
      gload_lds16(bsrc[2] + GOFF, smem + TB + 32768 + 2 * 8192 + dsto);
      gload_lds16(bsrc[3] + GOFF, smem + TB + 32768 + 3 * 8192 + dsto);
    }
    SB0();
    __builtin_amdgcn_s_setprio(1);
    asm volatile("s_waitcnt lgkmcnt(4)" ::: "memory");  // a4,a5 done
    SB0();
#pragma unroll
    for (int k = 0; k < 2; ++k)
#pragma unroll
      for (int mt = 0; mt < 2; ++mt)
#pragma unroll
        for (int nt = 0; nt < 2; ++nt)
          acc[4 + mt][2 + nt] = __builtin_amdgcn_mfma_f32_16x16x32_bf16(
              a[mt][k], bH[nt][k], acc[4 + mt][2 + nt], 0, 0, 0);
    asm volatile("s_waitcnt lgkmcnt(0)" ::: "memory");  // a6,a7 done
    SB0();
#pragma unroll
    for (int k = 0; k < 2; ++k)
#pragma unroll
      for (int mt = 2; mt < 4; ++mt)
#pragma unroll
        for (int nt = 0; nt < 2; ++nt)
          acc[4 + mt][2 + nt] = __builtin_amdgcn_mfma_f32_16x16x32_bf16(
              a[mt][k], bH[nt][k], acc[4 + mt][2 + nt], 0, 0, 0);
    __builtin_amdgcn_s_setprio(0);
    SB0();
    __builtin_amdgcn_s_barrier();   // aHi region dead block-wide

    // ---- P4: stage aHi(t+2); vmcnt; BAR; MFMA Q4 (reg-only); no end-BAR ----
    if constexpr (MODE == 0) {
      gload_lds16(asrc0 + 1 * 262144 + GOFF, smem + TB + 1 * 8192 + dsto);
      gload_lds16(asrc0 + 3 * 262144 + GOFF, smem + TB + 3 * 8192 + dsto);
      asm volatile("s_waitcnt vmcnt(8)" ::: "memory");  // tile t+1 landed
    } else if constexpr (MODE == 1) {
      asm volatile("s_waitcnt vmcnt(0)" ::: "memory");  // tile 31 landed
    }
    SB0();
    __builtin_amdgcn_s_barrier();   // slot t+1 collectively valid
    SB0();
    __builtin_amdgcn_s_setprio(1);
#pragma unroll
    for (int k = 0; k < 2; ++k)
#pragma unroll
      for (int mt = 0; mt < 4; ++mt)
#pragma unroll
        for (int nt = 0; nt < 2; ++nt)
          acc[4 + mt][nt] = __builtin_amdgcn_mfma_f32_16x16x32_bf16(
              a[mt][k], bL[nt][k], acc[4 + mt][nt], 0, 0, 0);
    __builtin_amdgcn_s_setprio(0);
    SB0();
    // (P4-end barrier removed in r18 — verified +5us, absmax clean.)
  };

#pragma unroll 1
  for (int T = 0; T < 15; ++T) {
    kstep(ic<0>{}, ic<0>{});
    kstep(ic<1>{}, ic<0>{});
    asrc0 += 256;
#pragma unroll
    for (int c = 0; c < 4; ++c) bsrc[c] += 256;
  }
  kstep(ic<0>{}, ic<1>{});   // t=30: no stage, vmcnt(0)
  kstep(ic<1>{}, ic<2>{});   // t=31: no stage, no vmcnt

  // ---- Epilogue: 16x16 C/D layout col=lane&15, row=(lane>>4)*4+reg ----
  const float alpha = alpha_p[0];
  const int rbase = bm * 256 + wm * 128 + q * 4;
  const int cbase = bn * 256 + wn * 64 + r15;
#pragma unroll
  for (int mt = 0; mt < 8; ++mt)
#pragma unroll
    for (int nt = 0; nt < 4; ++nt)
#pragma unroll
      for (int r = 0; r < 4; ++r)
        C[(size_t)(rbase + mt * 16 + r) * N_DIM + cbase + nt * 16] =
            alpha * acc[mt][nt][r];
}

// ---- Workspace-free fallback (round-1 verified structure, f32 reg-staged) ----
__global__ __launch_bounds__(256) void gemm_fallback(const float* __restrict__ Ap,
                                                     const float* __restrict__ Bp,
                                                     const float* __restrict__ alpha_p,
                                                     float* __restrict__ C) {
  __shared__ bf16_t Asf[128 * 32];
  __shared__ bf16_t Bsf[128 * 32];
  const int tid = threadIdx.x;
  const int lane = tid & 63;
  const int wid = tid >> 6;
  const int wr = wid >> 1;
  const int wc = wid & 1;
  const int cpx = gridDim.x >> 3;
  const int bid = blockIdx.x;
  const int swz = (bid & 7) * cpx + (bid >> 3);
  const int NB = N_DIM / 128;
  const int bm = swz / NB;
  const int bn = swz % NB;
  f32x4 acc[4][4];
#pragma unroll
  for (int m = 0; m < 4; ++m)
#pragma unroll
    for (int n = 0; n < 4; ++n) acc[m][n] = (f32x4){0.f, 0.f, 0.f, 0.f};
  const int r0 = lane & 15;
  const int ko = (lane >> 4) * 8;
  for (int kk = 0; kk < K_DIM; kk += 32) {
    const float* Af = Ap + (size_t)bm * 128 * K_DIM + kk;
    const float* Bf = Bp + (size_t)bn * 128 * K_DIM + kk;
#pragma unroll
    for (int qq = 0; qq < 4; ++qq) {
      int e = qq * 256 + tid;
      int row = e >> 3;
      int kc = (e & 7) << 2;
      float4 v = *(const float4*)(Af + (size_t)row * K_DIM + kc);
      bf16x4 tv;
      tv[0] = (bf16_t)v.x; tv[1] = (bf16_t)v.y; tv[2] = (bf16_t)v.z; tv[3] = (bf16_t)v.w;
      *(bf16x4*)&Asf[e * 4] = tv;
    }
#pragma unroll
    for (int qq = 0; qq < 4; ++qq) {
      int e = qq * 256 + tid;
      int row = e >> 3;
      int kc = (e & 7) << 2;
      float4 v = *(const float4*)(Bf + (size_t)row * K_DIM + kc);
      float s[4] = {v.x, v.y, v.z, v.w};
      bf16x4 tv;
#pragma unroll
      for (int j = 0; j < 4; ++j)
        tv[j] = (bf16_t)((s[j] > 0.f) ? 1.f : ((s[j] < 0.f) ? -1.f : 0.f));
      *(bf16x4*)&Bsf[e * 4] = tv;
    }
    __syncthreads();
    bf16x8 a[4], b[4];
#pragma unroll
    for (int m = 0; m < 4; ++m) a[m] = *(const bf16x8*)&Asf[(wr * 64 + m * 16 + r0) * 32 + ko];
#pragma unroll
    for (int n = 0; n < 4; ++n) b[n] = *(const bf16x8*)&Bsf[(wc * 64 + n * 16 + r0) * 32 + ko];
#pragma unroll
    for (int m = 0; m < 4; ++m)
#pragma unroll
      for (int n = 0; n < 4; ++n)
        acc[m][n] = __builtin_amdgcn_mfma_f32_16x16x32_bf16(a[m], b[n], acc[m][n], 0, 0, 0);
    __syncthreads();
  }
  const float alpha = alpha_p[0];
  const int rowb = bm * 128 + wr * 64 + (lane >> 4) * 4;
  const int colb = bn * 128 + wc * 64 + r0;
#pragma unroll
  for (int m = 0; m < 4; ++m)
#pragma unroll
    for (int n = 0; n < 4; ++n)
#pragma unroll
      for (int r = 0; r < 4; ++r)
        C[(size_t)(rowb + m * 16 + r) * N_DIM + colb + n * 16] = alpha * acc[m][n][r];
}

extern "C" void kernel_launch(void* const* d_in, const int* in_sizes, int n_in,
                              void* d_out, int out_size, void* d_ws, size_t ws_size,
                              hipStream_t stream) {
  const float* x = (const float*)d_in[0];
  const float* w = (const float*)d_in[1];
  const float* alpha = (const float*)d_in[2];
  float* out = (float*)d_out;

  const size_t nx = (size_t)M_DIM * K_DIM;
  const size_t nw = (size_t)N_DIM * K_DIM;
  const size_t need = (nx + nw) * sizeof(bf16_t);

  if (ws_size >= need) {
    bf16_t* xb = (bf16_t*)d_ws;
    bf16_t* wb = xb + nx;
    cvt_fused<<<NXB + NWB, 256, 0, stream>>>(x, w, xb, wb);
    (void)hipFuncSetAttribute((const void*)gemm12,
                              hipFuncAttributeMaxDynamicSharedMemorySize, 131072);
    gemm12<<<512, 512, 131072, stream>>>(xb, wb, alpha, out);
  } else {
    gemm_fallback<<<(M_DIM / 128) * (N_DIM / 128), 256, 0, stream>>>(x, w, alpha, out);
  }
}

// Round 23
// 154.693 us; speedup vs baseline: 1.0124x; 1.0124x over previous
//
#include <hip/hip_runtime.h>
#include <stdint.h>
#include <type_traits>

#define M_DIM 16384
#define N_DIM 2048
#define K_DIM 2048

typedef __bf16 bf16_t;
typedef __bf16 bf16x8 __attribute__((ext_vector_type(8)));
typedef __bf16 bf16x4 __attribute__((ext_vector_type(4)));
typedef float f32x4 __attribute__((ext_vector_type(4)));

template <int N> using ic = std::integral_constant<int, N>;

#define SB0() __builtin_amdgcn_sched_barrier(0)

__device__ __forceinline__ void gload_lds16(const void* g, void* l) {
  __builtin_amdgcn_global_load_lds(
      (const __attribute__((address_space(1))) void*)g,
      (__attribute__((address_space(3))) void*)l, 16, 0, 0);
}

// Fused converter (r12/r15-verified best): blocks [0,NXB) cvt x (bf16 RNE);
// blocks [NXB,NXB+NWB) cvt w with sign() (exact in bf16).
#define NXB (M_DIM * K_DIM / 2048)
#define NWB (N_DIM * K_DIM / 2048)
__global__ void cvt_fused(const float* __restrict__ x, const float* __restrict__ w,
                          bf16_t* __restrict__ xb, bf16_t* __restrict__ wb) {
  int b = blockIdx.x;
  const float* in = (b < NXB) ? x : w;
  bf16_t* out = (b < NXB) ? xb : wb;
  bool sign = (b >= NXB);
  if (b >= NXB) b -= NXB;
  long long i = ((long long)b * 256 + threadIdx.x) * 8;
  const float4* p = (const float4*)(in + i);
  float4 v0 = p[0];
  float4 v1 = p[1];
  float f[8] = {v0.x, v0.y, v0.z, v0.w, v1.x, v1.y, v1.z, v1.w};
  bf16x8 r;
#pragma unroll
  for (int j = 0; j < 8; ++j) {
    float v = f[j];
    if (sign) v = (v > 0.f) ? 1.f : ((v < 0.f) ? -1.f : 0.f);
    r[j] = (bf16_t)v;
  }
  *(bf16x8*)(out + i) = r;
}

// ============================================================================
// SESSION-FINAL GEMM = round-19 config, twice verified (155.0 / 154.85us
// total; GEMM 118.3-118.8us ~ 1160 TF = 46% dense peak; MfmaUtil 48.7-50%;
// 0 bank conflicts; VGPR 128 + AGPR 128; absmax 0.5 vs 2.46 threshold).
// Structure: 256x256 tile, BK=64, 8 waves (2Mx4N), 2x64KB LDS double-buffer.
// 4 phases/K-tile, 4 barriers/tile — each gating a PROVEN hazard:
//   P1: read aLo+bLo; lgkm0; Q1; BAR   (aLo/bLo dead -> P2 may stage them)
//   P2: read bHi; stage aLo+bLo(t+2); lgkm0; Q2; BAR  (bHi dead)
//   P3: read aHi; stage bHi(t+2);     lgkm0; Q3; BAR  (aHi dead)
//   P4: stage aHi(t+2); vmcnt(8); BAR (slot t+1 valid); Q4 reg-only; no
//       end-BAR (r18-proven dead, +5us).
// Counted vmcnt(8) keeps the 8 stage loads in flight ACROSS the barrier
// (never drains to 0 in the main loop); region-split staging gives each
// load 2-3 phases of MFMA cover. vmcnt(0)@t30, clean tail@t31.
// LDS swizzle phys_col = col ^ ((row&7)<<4) on 128B rows (0 conflicts);
// gload_lds writes linearly -> inverse-swizzled GLOBAL source (both-sides).
// Full 22-round evidence trail: barrier audit 8->7->4 gained +14us
// (r18/r19); 4->1 + per-tile vmcnt(0) REGRESSES 14us (r20 — drain, not
// barrier count, is the cost); intra-phase counted-lgkm streaming neutral-
// negative (r22 — sibling wave already covers read latency); registers
// saturated (r8/r10 spills); 0-conflict 32x32-MFMA variant identical (r16);
// 2-blocks/CU identical (r11); NT stores regress (r13); i8/fp8 x-quant
// exceeds absmax budget. Remaining gap to ~70% is the co-designed
// producer/consumer stack — not reachable by safe incremental steps here.
// ============================================================================
__global__ __launch_bounds__(512, 2) void gemm12(const bf16_t* __restrict__ A,
                                                 const bf16_t* __restrict__ B,
                                                 const float* __restrict__ alpha_p,
                                                 float* __restrict__ C) {
  extern __shared__ char smem[];  // buf(t&1): A @ tb+0 (32KB), B @ tb+32768

  const int tid = threadIdx.x;
  const int lane = tid & 63;
  const int wid = tid >> 6;
  const int wm = wid >> 2;   // 0..1 -> rows wm*128..+127
  const int wn = wid & 3;    // 0..3 -> cols wn*64..+63

  // XCD-aware bijective swizzle (512 blocks, 512 % 8 == 0)
  const int bid = blockIdx.x;
  const int swz = (bid & 7) * 64 + (bid >> 3);
  const int bm = swz >> 3;   // 0..63
  const int bn = swz & 7;    // 0..7

  const int q = lane >> 4;   // 16B col-slot within K
  const int r15 = lane & 15; // frag row

  // ---- Fragment LDS byte bases ----
  const int swc = (r15 & 7) << 4;
  int aoff[2], boffL[2], boffH[2];
#pragma unroll
  for (int k = 0; k < 2; ++k) {
    int ck = (k * 64 + q * 16) ^ swc;
    aoff[k] = (wm * 128 + r15) * 128 + ck;                 // + mt*2048
    boffL[k] = 32768 + (wn * 32 + r15) * 128 + ck;         // + nt*2048 (nt 0,1)
    boffH[k] = 32768 + 16384 + (wn * 32 + r15) * 128 + ck; // + (nt-2)*2048
  }

  // ---- Stage sources: inverse-swizzled global, linear LDS dest ----
  const char* asrc0;
  {
    int P = tid * 16;
    int row = P >> 7;
    int lcol = (P & 127) ^ ((row & 7) << 4);
    asrc0 = (const char*)A + (size_t)(bm * 256 + row) * (K_DIM * 2) + lcol;
  }
  const char* bsrc[4];
#pragma unroll
  for (int c = 0; c < 4; ++c) {
    int P = c * 8192 + tid * 16;
    int lr = P >> 7;                       // LDS row 0..255
    int grow;
    if (lr < 128) grow = (lr >> 5) * 64 + (lr & 31);          // bLo
    else { int l2 = lr - 128; grow = (l2 >> 5) * 64 + 32 + (l2 & 31); }  // bHi
    int lcol = (P & 127) ^ ((lr & 7) << 4);
    bsrc[c] = (const char*)B + (size_t)(bn * 256 + grow) * (K_DIM * 2) + lcol;
  }
  const int dsto = wid * 1024;

  f32x4 acc[8][4];
#pragma unroll
  for (int mt = 0; mt < 8; ++mt)
#pragma unroll
    for (int nt = 0; nt < 4; ++nt) acc[mt][nt] = (f32x4){0.f, 0.f, 0.f, 0.f};

  // ---- Prologue: stage tiles 0,1 (16 loads); wait tile 0 (8 younger) ----
#pragma unroll
  for (int t = 0; t < 2; ++t) {
#pragma unroll
    for (int j = 0; j < 4; ++j)
      gload_lds16(asrc0 + (size_t)j * 262144 + t * 128,
                  smem + t * 65536 + j * 8192 + dsto);
#pragma unroll
    for (int c = 0; c < 4; ++c)
      gload_lds16(bsrc[c] + t * 128, smem + t * 65536 + 32768 + c * 8192 + dsto);
  }
  asm volatile("s_waitcnt vmcnt(8)" ::: "memory");
  SB0();
  __builtin_amdgcn_s_barrier();
  SB0();

  // One K-tile (BK=64, 4 phases, 4 barriers). U = t&1. MODE: 0 steady
  // (stage t+2, vmcnt(8)); 1 = t=30 (no stage, vmcnt(0)); 2 = t=31 (none).
  auto kstep = [&](auto UC, auto MC) {
    constexpr int U = UC.value;
    constexpr int MODE = MC.value;
    constexpr int TB = U * 65536;
    constexpr int GOFF = (U + 2) * 128;

    bf16x8 a[4][2], bL[2][2], bH[2][2];

    // ---- P1: read aLo(8)+bLo(4); lgkm0; MFMA Q1; BAR ----
#pragma unroll
    for (int mt = 0; mt < 4; ++mt)
#pragma unroll
      for (int k = 0; k < 2; ++k)
        a[mt][k] = *(const bf16x8*)(smem + TB + aoff[k] + mt * 2048);
#pragma unroll
    for (int nt = 0; nt < 2; ++nt)
#pragma unroll
      for (int k = 0; k < 2; ++k)
        bL[nt][k] = *(const bf16x8*)(smem + TB + boffL[k] + nt * 2048);
    SB0();
    asm volatile("s_waitcnt lgkmcnt(0)" ::: "memory");
    SB0();
    __builtin_amdgcn_s_setprio(1);
#pragma unroll
    for (int k = 0; k < 2; ++k)
#pragma unroll
      for (int mt = 0; mt < 4; ++mt)
#pragma unroll
        for (int nt = 0; nt < 2; ++nt)
          acc[mt][nt] = __builtin_amdgcn_mfma_f32_16x16x32_bf16(
              a[mt][k], bL[nt][k], acc[mt][nt], 0, 0, 0);
    __builtin_amdgcn_s_setprio(0);
    SB0();
    __builtin_amdgcn_s_barrier();   // aLo/bLo regions dead block-wide

    // ---- P2: read bHi(4); stage aLo+bLo(t+2); lgkm0; MFMA Q2; BAR ----
#pragma unroll
    for (int nt = 0; nt < 2; ++nt)
#pragma unroll
      for (int k = 0; k < 2; ++k)
        bH[nt][k] = *(const bf16x8*)(smem + TB + boffH[k] + nt * 2048);
    if constexpr (MODE == 0) {
      gload_lds16(asrc0 + 0 * 262144 + GOFF, smem + TB + 0 * 8192 + dsto);
      gload_lds16(asrc0 + 2 * 262144 + GOFF, smem + TB + 2 * 8192 + dsto);
      gload_lds16(bsrc[0] + GOFF, smem + TB + 32768 + 0 * 8192 + dsto);
      gload_lds16(bsrc[1] + GOFF, smem + TB + 32768 + 1 * 8192 + dsto);
    }
    SB0();
    asm volatile("s_waitcnt lgkmcnt(0)" ::: "memory");
    SB0();
    __builtin_amdgcn_s_setprio(1);
#pragma unroll
    for (int k = 0; k < 2; ++k)
#pragma unroll
      for (int mt = 0; mt < 4; ++mt)
#pragma unroll
        for (int nt = 0; nt < 2; ++nt)
          acc[mt][2 + nt] = __builtin_amdgcn_mfma_f32_16x16x32_bf16(
              a[mt][k], bH[nt][k], acc[mt][2 + nt], 0, 0, 0);
    __builtin_amdgcn_s_setprio(0);
    SB0();
    __builtin_amdgcn_s_barrier();   // bHi region dead block-wide

    // ---- P3: read aHi(8); stage bHi(t+2); lgkm0; MFMA Q3; BAR ----
#pragma unroll
    for (int mt = 0; mt < 4; ++mt)
#pragma unroll
      for (int k = 0; k < 2; ++k)
        a[mt][k] = *(const bf16x8*)(smem + TB + aoff[k] + (4 + mt) * 2048);
    if constexpr (MODE == 0) {
      gload_lds16(bsrc[2] + GOFF, smem + TB + 32768 + 2 * 8192 + dsto);
      gload_lds16(bsrc[3] + GOFF, smem + TB + 32768 + 3 * 8192 + dsto);
    }
    SB0();
    asm volatile("s_waitcnt lgkmcnt(0)" ::: "memory");
    SB0();
    __builtin_amdgcn_s_setprio(1);
#pragma unroll
    for (int k = 0; k < 2; ++k)
#pragma unroll
      for (int mt = 0; mt < 4; ++mt)
#pragma unroll
        for (int nt = 0; nt < 2; ++nt)
          acc[4 + mt][2 + nt] = __builtin_amdgcn_mfma_f32_16x16x32_bf16(
              a[mt][k], bH[nt][k], acc[4 + mt][2 + nt], 0, 0, 0);
    __builtin_amdgcn_s_setprio(0);
    SB0();
    __builtin_amdgcn_s_barrier();   // aHi region dead block-wide

    // ---- P4: stage aHi(t+2); vmcnt; BAR; MFMA Q4 (reg-only); no end-BAR ----
    if constexpr (MODE == 0) {
      gload_lds16(asrc0 + 1 * 262144 + GOFF, smem + TB + 1 * 8192 + dsto);
      gload_lds16(asrc0 + 3 * 262144 + GOFF, smem + TB + 3 * 8192 + dsto);
      asm volatile("s_waitcnt vmcnt(8)" ::: "memory");  // tile t+1 landed
    } else if constexpr (MODE == 1) {
      asm volatile("s_waitcnt vmcnt(0)" ::: "memory");  // tile 31 landed
    }
    SB0();
    __builtin_amdgcn_s_barrier();   // slot t+1 collectively valid
    SB0();
    __builtin_amdgcn_s_setprio(1);
#pragma unroll
    for (int k = 0; k < 2; ++k)
#pragma unroll
      for (int mt = 0; mt < 4; ++mt)
#pragma unroll
        for (int nt = 0; nt < 2; ++nt)
          acc[4 + mt][nt] = __builtin_amdgcn_mfma_f32_16x16x32_bf16(
              a[mt][k], bL[nt][k], acc[4 + mt][nt], 0, 0, 0);
    __builtin_amdgcn_s_setprio(0);
    SB0();
    // (P4-end barrier removed in r18 — verified +5us, absmax clean.)
  };

#pragma unroll 1
  for (int T = 0; T < 15; ++T) {
    kstep(ic<0>{}, ic<0>{});
    kstep(ic<1>{}, ic<0>{});
    asrc0 += 256;
#pragma unroll
    for (int c = 0; c < 4; ++c) bsrc[c] += 256;
  }
  kstep(ic<0>{}, ic<1>{});   // t=30: no stage, vmcnt(0)
  kstep(ic<1>{}, ic<2>{});   // t=31: no stage, no vmcnt

  // ---- Epilogue: 16x16 C/D layout col=lane&15, row=(lane>>4)*4+reg ----
  const float alpha = alpha_p[0];
  const int rbase = bm * 256 + wm * 128 + q * 4;
  const int cbase = bn * 256 + wn * 64 + r15;
#pragma unroll
  for (int mt = 0; mt < 8; ++mt)
#pragma unroll
    for (int nt = 0; nt < 4; ++nt)
#pragma unroll
      for (int r = 0; r < 4; ++r)
        C[(size_t)(rbase + mt * 16 + r) * N_DIM + cbase + nt * 16] =
            alpha * acc[mt][nt][r];
}

// ---- Workspace-free fallback (round-1 verified structure, f32 reg-staged) ----
__global__ __launch_bounds__(256) void gemm_fallback(const float* __restrict__ Ap,
                                                     const float* __restrict__ Bp,
                                                     const float* __restrict__ alpha_p,
                                                     float* __restrict__ C) {
  __shared__ bf16_t Asf[128 * 32];
  __shared__ bf16_t Bsf[128 * 32];
  const int tid = threadIdx.x;
  const int lane = tid & 63;
  const int wid = tid >> 6;
  const int wr = wid >> 1;
  const int wc = wid & 1;
  const int cpx = gridDim.x >> 3;
  const int bid = blockIdx.x;
  const int swz = (bid & 7) * cpx + (bid >> 3);
  const int NB = N_DIM / 128;
  const int bm = swz / NB;
  const int bn = swz % NB;
  f32x4 acc[4][4];
#pragma unroll
  for (int m = 0; m < 4; ++m)
#pragma unroll
    for (int n = 0; n < 4; ++n) acc[m][n] = (f32x4){0.f, 0.f, 0.f, 0.f};
  const int r0 = lane & 15;
  const int ko = (lane >> 4) * 8;
  for (int kk = 0; kk < K_DIM; kk += 32) {
    const float* Af = Ap + (size_t)bm * 128 * K_DIM + kk;
    const float* Bf = Bp + (size_t)bn * 128 * K_DIM + kk;
#pragma unroll
    for (int qq = 0; qq < 4; ++qq) {
      int e = qq * 256 + tid;
      int row = e >> 3;
      int kc = (e & 7) << 2;
      float4 v = *(const float4*)(Af + (size_t)row * K_DIM + kc);
      bf16x4 tv;
      tv[0] = (bf16_t)v.x; tv[1] = (bf16_t)v.y; tv[2] = (bf16_t)v.z; tv[3] = (bf16_t)v.w;
      *(bf16x4*)&Asf[e * 4] = tv;
    }
#pragma unroll
    for (int qq = 0; qq < 4; ++qq) {
      int e = qq * 256 + tid;
      int row = e >> 3;
      int kc = (e & 7) << 2;
      float4 v = *(const float4*)(Bf + (size_t)row * K_DIM + kc);
      float s[4] = {v.x, v.y, v.z, v.w};
      bf16x4 tv;
#pragma unroll
      for (int j = 0; j < 4; ++j)
        tv[j] = (bf16_t)((s[j] > 0.f) ? 1.f : ((s[j] < 0.f) ? -1.f : 0.f));
      *(bf16x4*)&Bsf[e * 4] = tv;
    }
    __syncthreads();
    bf16x8 a[4], b[4];
#pragma unroll
    for (int m = 0; m < 4; ++m) a[m] = *(const bf16x8*)&Asf[(wr * 64 + m * 16 + r0) * 32 + ko];
#pragma unroll
    for (int n = 0; n < 4; ++n) b[n] = *(const bf16x8*)&Bsf[(wc * 64 + n * 16 + r0) * 32 + ko];
#pragma unroll
    for (int m = 0; m < 4; ++m)
#pragma unroll
      for (int n = 0; n < 4; ++n)
        acc[m][n] = __builtin_amdgcn_mfma_f32_16x16x32_bf16(a[m], b[n], acc[m][n], 0, 0, 0);
    __syncthreads();
  }
  const float alpha = alpha_p[0];
  const int rowb = bm * 128 + wr * 64 + (lane >> 4) * 4;
  const int colb = bn * 128 + wc * 64 + r0;
#pragma unroll
  for (int m = 0; m < 4; ++m)
#pragma unroll
    for (int n = 0; n < 4; ++n)
#pragma unroll
      for (int r = 0; r < 4; ++r)
        C[(size_t)(rowb + m * 16 + r) * N_DIM + colb + n * 16] = alpha * acc[m][n][r];
}

extern "C" void kernel_launch(void* const* d_in, const int* in_sizes, int n_in,
                              void* d_out, int out_size, void* d_ws, size_t ws_size,
                              hipStream_t stream) {
  const float* x = (const float*)d_in[0];
  const float* w = (const float*)d_in[1];
  const float* alpha = (const float*)d_in[2];
  float* out = (float*)d_out;

  const size_t nx = (size_t)M_DIM * K_DIM;
  const size_t nw = (size_t)N_DIM * K_DIM;
  const size_t need = (nx + nw) * sizeof(bf16_t);

  if (ws_size >= need) {
    bf16_t* xb = (bf16_t*)d_ws;
    bf16_t* wb = xb + nx;
    cvt_fused<<<NXB + NWB, 256, 0, stream>>>(x, w, xb, wb);
    (void)hipFuncSetAttribute((const void*)gemm12,
                              hipFuncAttributeMaxDynamicSharedMemorySize, 131072);
    gemm12<<<512, 512, 131072, stream>>>(xb, wb, alpha, out);
  } else {
    gemm_fallback<<<(M_DIM / 128) * (N_DIM / 128), 256, 0, stream>>>(x, w, alpha, out);
  }
}